// Round 6
// baseline (251.911 us; speedup 1.0000x reference)
//
#include <hip/hip_runtime.h>

#define N_NODES 100000
#define N_EDGES 1000000
#define D_IN    256
#define D_OUT   64

// 32-node buckets (round 5): exclusive per-wave agg accumulators, no atomics.
#define BKT_SHIFT   5
#define NODES_PER_BKT 32
#define N_BKT       3125           // 100000 / 32 exact
#define BKT_CAP     512            // mean 320, sigma ~18 -> +10 sigma slack

// Round 6: bin split from GEMM and spread over ~2 blocks/CU. Total LDS-atomic
// work is fixed (2 atomics/edge, ~3.2 cyc/lane, round-4 calibration); more
// blocks = more LDS units in parallel.
#define EPB         2048           // edges per binning block
#define BIN_BLOCKS  489            // ceil(1e6 / 2048)
#define GEMM_BLOCKS 782            // 3128 waves, 2 tiles/wave, 6250 tiles exact
#define NUM_TILES   6250           // 100000 / 16 exactly
#define AGG_BLOCKS  391            // ceil(3125 buckets / 8 waves)

typedef __attribute__((ext_vector_type(8))) short short8;
typedef __attribute__((ext_vector_type(4))) float f32x4;

__device__ __forceinline__ unsigned short f2bf(float f) {
    unsigned int u = __float_as_uint(f);
    u = (u + 0x7fffu + ((u >> 16) & 1u)) >> 16;
    return (unsigned short)u;
}

// MFMA + store for one 16-row tile; B read from LDS per use (keeps VGPRs for
// the A-load pipeline). wT pad = 272 shorts (544 B = 8 banks offset/row ->
// 4-way b128 aliasing instead of 8-way at 264).
__device__ __forceinline__ void mfma_store_tile(
    const short8 afrag[8], const unsigned short wT[64][272],
    unsigned short* __restrict__ hiddenBf, int r0, int n16, int quad)
{
    f32x4 acc[4] = {{0.f,0.f,0.f,0.f},{0.f,0.f,0.f,0.f},
                    {0.f,0.f,0.f,0.f},{0.f,0.f,0.f,0.f}};
#pragma unroll
    for (int ct = 0; ct < 4; ++ct) {
#pragma unroll
        for (int kk = 0; kk < 8; ++kk) {
            short8 b = *(const short8*)&wT[ct * 16 + n16][kk * 32 + quad * 8];
            acc[ct] = __builtin_amdgcn_mfma_f32_16x16x32_bf16(
                afrag[kk], b, acc[ct], 0, 0, 0);
        }
    }
    // C/D layout: col = lane&15, row = quad*4 + reg  [m89-verified]
#pragma unroll
    for (int ct = 0; ct < 4; ++ct)
#pragma unroll
        for (int reg = 0; reg < 4; ++reg)
            hiddenBf[(size_t)(r0 + quad * 4 + reg) * D_OUT + ct * 16 + n16]
                = f2bf(acc[ct][reg]);
}

// ---------------------------------------------------------------------------
// Round 6: standalone bin kernel, 489 blocks (~2/CU). Per thread: 8 edges.
// pass 1: batched row loads + LDS hist; pass 3: per-bucket global
// atomic-return reserves the window; pass 4: batched col/adj + LDS
// cursor-return + scatter store. LDS 37.5 KB -> 4 blocks/CU possible.
// ---------------------------------------------------------------------------
__global__ __launch_bounds__(256, 2) void bin_kernel(
    const int* __restrict__ row, const int* __restrict__ col,
    const float* __restrict__ adj, int* __restrict__ gCursor,
    int2* __restrict__ edges)
{
    __shared__ int cnt[N_BKT];
    __shared__ int cbase[N_BKT];
    __shared__ int cur[N_BKT];

    const int t  = threadIdx.x;
    const int e0 = blockIdx.x * EPB;

    for (int i = t; i < N_BKT; i += 256) cnt[i] = 0;
    __syncthreads();

    // pass 1: 8 batched row loads (all in flight), kept for pass 4
    int rreg[8];
#pragma unroll
    for (int u = 0; u < 8; ++u) {
        int e = e0 + t + u * 256;
        rreg[u] = (e < N_EDGES) ? row[e] : -1;
    }
#pragma unroll
    for (int u = 0; u < 8; ++u)
        if (rreg[u] >= 0) atomicAdd(&cnt[rreg[u] >> BKT_SHIFT], 1);
    __syncthreads();

    for (int i = t; i < N_BKT; i += 256) {
        int c = cnt[i];
        cbase[i] = c ? atomicAdd(&gCursor[i], c) : 0;
        cur[i] = 0;
    }
    __syncthreads();

    // pass 4: batched col/adj (16 loads in flight), then 8 independent
    // LDS-cursor-return + scatter-store pairs.
    int cc[8]; float vv[8];
#pragma unroll
    for (int u = 0; u < 8; ++u) {
        int e = e0 + t + u * 256;
        if (rreg[u] >= 0) { cc[u] = col[e]; vv[u] = adj[e]; }
        else              { cc[u] = 0;      vv[u] = 0.f;    }
    }
#pragma unroll
    for (int u = 0; u < 8; ++u) {
        int r = rreg[u];
        if (r >= 0) {
            int b = r >> BKT_SHIFT;
            int off = cbase[b] + atomicAdd(&cur[b], 1);
            if (off < BKT_CAP) {  // capacity guard (never trips)
                edges[b * BKT_CAP + off] =
                    make_int2(((r & (NODES_PER_BKT - 1)) << 17) | cc[u],
                              __float_as_int(vv[u]));
            }
        }
    }
}

// ---------------------------------------------------------------------------
// Round 6: standalone GEMM kernel (path unchanged from round 3). LDS = wT
// only (34.8 KB) -> 4 blocks/CU, 16 waves/CU: pure BW regime.
// ---------------------------------------------------------------------------
__global__ __launch_bounds__(256, 2) void gemm_kernel(
    const float* __restrict__ x, const float* __restrict__ w,
    unsigned short* __restrict__ hiddenBf)
{
    const int t = threadIdx.x;

    __shared__ unsigned short wT[64][272];

    for (int i = 0; i < 64; ++i) {
        int idx = t + i * 256;
        int k = idx >> 6, n = idx & 63;
        wT[n][k] = f2bf(w[idx]);
    }
    __syncthreads();

    const int lane = t & 63;
    const int wid  = t >> 6;
    const int n16  = lane & 15;
    const int quad = lane >> 4;

    const int waveGid = blockIdx.x * 4 + wid;
    const int t0 = waveGid * 2;
    if (t0 >= NUM_TILES) return;

    float4 lo[8], hi[8];
    short8 afrag[8];

    // prologue: issue all 16 loads of tile t0
    {
        const float* xrow = x + (size_t)(t0 * 16 + n16) * D_IN + quad * 8;
#pragma unroll
        for (int kk = 0; kk < 8; ++kk) {
            lo[kk] = *(const float4*)(xrow + kk * 32);
            hi[kk] = *(const float4*)(xrow + kk * 32 + 4);
        }
    }
    // convert tile t0 (forces one waitcnt), freeing lo/hi
#pragma unroll
    for (int kk = 0; kk < 8; ++kk) {
        short8 a;
        a[0] = (short)f2bf(lo[kk].x); a[1] = (short)f2bf(lo[kk].y);
        a[2] = (short)f2bf(lo[kk].z); a[3] = (short)f2bf(lo[kk].w);
        a[4] = (short)f2bf(hi[kk].x); a[5] = (short)f2bf(hi[kk].y);
        a[6] = (short)f2bf(hi[kk].z); a[7] = (short)f2bf(hi[kk].w);
        afrag[kk] = a;
    }

    const int t1 = t0 + 1;
    const bool have1 = t1 < NUM_TILES;
    if (have1) {
        // issue tile t1's 16 loads BEFORE tile t0's MFMA/store
        const float* xrow = x + (size_t)(t1 * 16 + n16) * D_IN + quad * 8;
#pragma unroll
        for (int kk = 0; kk < 8; ++kk) {
            lo[kk] = *(const float4*)(xrow + kk * 32);
            hi[kk] = *(const float4*)(xrow + kk * 32 + 4);
        }
    }

    mfma_store_tile(afrag, wT, hiddenBf, t0 * 16, n16, quad);

    if (have1) {
#pragma unroll
        for (int kk = 0; kk < 8; ++kk) {
            short8 a;
            a[0] = (short)f2bf(lo[kk].x); a[1] = (short)f2bf(lo[kk].y);
            a[2] = (short)f2bf(lo[kk].z); a[3] = (short)f2bf(lo[kk].w);
            a[4] = (short)f2bf(hi[kk].x); a[5] = (short)f2bf(hi[kk].y);
            a[6] = (short)f2bf(hi[kk].z); a[7] = (short)f2bf(hi[kk].w);
            afrag[kk] = a;
        }
        mfma_store_tile(afrag, wT, hiddenBf, t1 * 16, n16, quad);
    }
}

// ---------------------------------------------------------------------------
// Ownership-partitioned bucket aggregation (round 5 structure). Round 6:
// gather pipeline deepened to 16 in-flight hiddenBf rows per wave (was 8)
// to halve exposed L2/L3 latency per edge. Exclusive 8-KB LDS slice per
// wave -> plain non-atomic RMW; no barriers.
// ---------------------------------------------------------------------------
__global__ __launch_bounds__(512, 2) void bucket_agg_kernel(
    const unsigned short* __restrict__ hiddenBf,
    const int2* __restrict__ edges, const int* __restrict__ gCursor,
    const float* __restrict__ prelu_a, float* __restrict__ out)
{
    __shared__ float acc[8][NODES_PER_BKT * D_OUT];   // 8 x 8 KB = 64 KB

    const int t      = threadIdx.x;
    const int lane   = t & 63;
    const int wid    = t >> 6;
    const int bucket = blockIdx.x * 8 + wid;
    if (bucket >= N_BKT) return;      // safe: no barriers in this kernel

    float* A = acc[wid];

    // zero this wave's slice: 2048 floats = 512 float4, 8 per lane
    float4* A4 = (float4*)A;
#pragma unroll
    for (int i = 0; i < 8; ++i)
        A4[lane + i * 64] = make_float4(0.f, 0.f, 0.f, 0.f);

    const int base = bucket * BKT_CAP;
    int size = gCursor[bucket];
    if (size > BKT_CAP) size = BKT_CAP;

    for (int i0 = 0; i0 < size; i0 += 64) {
        int take = size - i0;
        if (take > 64) take = 64;
        int2 rec = make_int2(0, 0);
        if (lane < take) rec = edges[base + i0 + lane];

        int j = 0;
        // 16-deep: 16 coalesced 128-B row gathers in flight per wave
        for (; j + 16 <= take; j += 16) {
            int nl[16]; int c[16]; float v[16]; float h[16];
#pragma unroll
            for (int u = 0; u < 16; ++u) {
                int rx = __builtin_amdgcn_readlane(rec.x, j + u);
                nl[u] = (unsigned)rx >> 17;              // node_local in [0,32)
                c[u]  = rx & 0x1FFFF;
                v[u]  = __int_as_float(__builtin_amdgcn_readlane(rec.y, j + u));
            }
#pragma unroll
            for (int u = 0; u < 16; ++u)
                h[u] = __uint_as_float(
                    (unsigned)hiddenBf[(size_t)c[u] * D_OUT + lane] << 16);
#pragma unroll
            for (int u = 0; u < 16; ++u)
                A[nl[u] * D_OUT + lane] += v[u] * h[u];
        }
        for (; j + 8 <= take; j += 8) {
            int nl[8]; int c[8]; float v[8]; float h[8];
#pragma unroll
            for (int u = 0; u < 8; ++u) {
                int rx = __builtin_amdgcn_readlane(rec.x, j + u);
                nl[u] = (unsigned)rx >> 17;
                c[u]  = rx & 0x1FFFF;
                v[u]  = __int_as_float(__builtin_amdgcn_readlane(rec.y, j + u));
            }
#pragma unroll
            for (int u = 0; u < 8; ++u)
                h[u] = __uint_as_float(
                    (unsigned)hiddenBf[(size_t)c[u] * D_OUT + lane] << 16);
#pragma unroll
            for (int u = 0; u < 8; ++u)
                A[nl[u] * D_OUT + lane] += v[u] * h[u];
        }
        for (; j < take; ++j) {
            int rx  = __builtin_amdgcn_readlane(rec.x, j);
            float v = __int_as_float(__builtin_amdgcn_readlane(rec.y, j));
            float h = __uint_as_float(
                (unsigned)hiddenBf[(size_t)(rx & 0x1FFFF) * D_OUT + lane] << 16);
            A[((unsigned)rx >> 17) * D_OUT + lane] += v * h;
        }
    }

    // epilogue: PReLU + coalesced store (wave writes its 32 nodes x 64 dims)
    const float a = prelu_a[0];
    const int node0 = bucket * NODES_PER_BKT;
#pragma unroll
    for (int i = 0; i < NODES_PER_BKT; ++i) {
        float s = A[i * D_OUT + lane];
        out[(size_t)(node0 + i) * D_OUT + lane] = s > 0.f ? s : a * s;
    }
}

// ---------------------------------------------------------------------------
extern "C" void kernel_launch(void* const* d_in, const int* in_sizes, int n_in,
                              void* d_out, int out_size, void* d_ws, size_t ws_size,
                              hipStream_t stream)
{
    const float* x       = (const float*)d_in[0];
    const float* w       = (const float*)d_in[1];
    const float* adj     = (const float*)d_in[2];
    const float* prelu_a = (const float*)d_in[3];
    const int*   row     = (const int*)d_in[4];
    const int*   col     = (const int*)d_in[5];
    float* out = (float*)d_out;

    // workspace layout (bytes)
    char* ws = (char*)d_ws;
    unsigned short* hiddenBf = (unsigned short*)(ws);        // 12,800,000
    int2*  edges    = (int2*)        (ws + 12800000);        // 12,800,000 (3125*512*8)
    int*   gCursor  = (int*)         (ws + 25600000);        //     12,500

    hipMemsetAsync(gCursor, 0, N_BKT * sizeof(int), stream);

    bin_kernel<<<BIN_BLOCKS, 256, 0, stream>>>(row, col, adj, gCursor, edges);

    gemm_kernel<<<GEMM_BLOCKS, 256, 0, stream>>>(x, w, hiddenBf);

    bucket_agg_kernel<<<AGG_BLOCKS, 512, 0, stream>>>(
        hiddenBf, edges, gCursor, prelu_a, out);
}

// Round 7
// 240.290 us; speedup vs baseline: 1.0484x; 1.0484x over previous
//
#include <hip/hip_runtime.h>

#define N_NODES 100000
#define N_EDGES 1000000
#define D_IN    256
#define D_OUT   64

// Round 7: 16-node buckets (100000/16 = 6250 exact). Aggregation is done on
// the MFMA as out[16n x 64d] = P[16 x E] @ H[E x 64d] per bucket, with P a
// register-built selector (adj split hi/lo bf16 in bin for precision) and H
// staged transposed in LDS (wT pattern -> verified fragment layouts).
#define BKT_SHIFT   4
#define NODES_PER_BKT 16
#define N_BKT       6250
#define BKT_CAP     256            // mean 160, sigma ~12.6 -> +7.6 sigma
#define EPB         2048           // edges per binning block
#define BIN_BLOCKS  489            // ceil(1e6 / 2048)
#define GEMM_BLOCKS 782            // 3128 waves, 2 tiles/wave, 6250 tiles exact
#define NUM_TILES   6250           // 100000 / 16 exactly
#define AGG_BLOCKS  782            // 8 wave-buckets/block -> 6256 >= 6250

typedef __attribute__((ext_vector_type(8))) short short8;
typedef __attribute__((ext_vector_type(4))) float f32x4;
typedef __attribute__((ext_vector_type(4))) unsigned short u16x4;

__device__ __forceinline__ unsigned short f2bf(float f) {
    unsigned int u = __float_as_uint(f);
    u = (u + 0x7fffu + ((u >> 16) & 1u)) >> 16;
    return (unsigned short)u;
}

// MFMA + store for one 16-row tile; B read from LDS per use (keeps VGPRs for
// the A-load pipeline). wT pad = 272 shorts (544 B = 8 banks offset/row ->
// 4-way b128 aliasing instead of 8-way at 264).
__device__ __forceinline__ void mfma_store_tile(
    const short8 afrag[8], const unsigned short wT[64][272],
    unsigned short* __restrict__ hiddenBf, int r0, int n16, int quad)
{
    f32x4 acc[4] = {{0.f,0.f,0.f,0.f},{0.f,0.f,0.f,0.f},
                    {0.f,0.f,0.f,0.f},{0.f,0.f,0.f,0.f}};
#pragma unroll
    for (int ct = 0; ct < 4; ++ct) {
#pragma unroll
        for (int kk = 0; kk < 8; ++kk) {
            short8 b = *(const short8*)&wT[ct * 16 + n16][kk * 32 + quad * 8];
            acc[ct] = __builtin_amdgcn_mfma_f32_16x16x32_bf16(
                afrag[kk], b, acc[ct], 0, 0, 0);
        }
    }
    // C/D layout: col = lane&15, row = quad*4 + reg  [m89-verified]
#pragma unroll
    for (int ct = 0; ct < 4; ++ct)
#pragma unroll
        for (int reg = 0; reg < 4; ++reg)
            hiddenBf[(size_t)(r0 + quad * 4 + reg) * D_OUT + ct * 16 + n16]
                = f2bf(acc[ct][reg]);
}

// ---------------------------------------------------------------------------
// GEMM kernel (path unchanged). Launched FIRST; block 0 zeroes gCursor so
// the hipMemsetAsync dispatch (suspect ~60 us fillBuffer) is eliminated.
// Stream order guarantees gCursor is zero before bin_kernel starts.
// ---------------------------------------------------------------------------
__global__ __launch_bounds__(256, 2) void gemm_kernel(
    const float* __restrict__ x, const float* __restrict__ w,
    unsigned short* __restrict__ hiddenBf, int* __restrict__ gCursor)
{
    const int t = threadIdx.x;

    if (blockIdx.x == 0) {
        for (int i = t; i < N_BKT; i += 256) gCursor[i] = 0;
    }

    __shared__ unsigned short wT[64][272];

    for (int i = 0; i < 64; ++i) {
        int idx = t + i * 256;
        int k = idx >> 6, n = idx & 63;
        wT[n][k] = f2bf(w[idx]);
    }
    __syncthreads();

    const int lane = t & 63;
    const int wid  = t >> 6;
    const int n16  = lane & 15;
    const int quad = lane >> 4;

    const int waveGid = blockIdx.x * 4 + wid;
    const int t0 = waveGid * 2;
    if (t0 >= NUM_TILES) return;

    float4 lo[8], hi[8];
    short8 afrag[8];

    // prologue: issue all 16 loads of tile t0
    {
        const float* xrow = x + (size_t)(t0 * 16 + n16) * D_IN + quad * 8;
#pragma unroll
        for (int kk = 0; kk < 8; ++kk) {
            lo[kk] = *(const float4*)(xrow + kk * 32);
            hi[kk] = *(const float4*)(xrow + kk * 32 + 4);
        }
    }
#pragma unroll
    for (int kk = 0; kk < 8; ++kk) {
        short8 a;
        a[0] = (short)f2bf(lo[kk].x); a[1] = (short)f2bf(lo[kk].y);
        a[2] = (short)f2bf(lo[kk].z); a[3] = (short)f2bf(lo[kk].w);
        a[4] = (short)f2bf(hi[kk].x); a[5] = (short)f2bf(hi[kk].y);
        a[6] = (short)f2bf(hi[kk].z); a[7] = (short)f2bf(hi[kk].w);
        afrag[kk] = a;
    }

    const int t1 = t0 + 1;
    const bool have1 = t1 < NUM_TILES;
    if (have1) {
        const float* xrow = x + (size_t)(t1 * 16 + n16) * D_IN + quad * 8;
#pragma unroll
        for (int kk = 0; kk < 8; ++kk) {
            lo[kk] = *(const float4*)(xrow + kk * 32);
            hi[kk] = *(const float4*)(xrow + kk * 32 + 4);
        }
    }

    mfma_store_tile(afrag, wT, hiddenBf, t0 * 16, n16, quad);

    if (have1) {
#pragma unroll
        for (int kk = 0; kk < 8; ++kk) {
            short8 a;
            a[0] = (short)f2bf(lo[kk].x); a[1] = (short)f2bf(lo[kk].y);
            a[2] = (short)f2bf(lo[kk].z); a[3] = (short)f2bf(lo[kk].w);
            a[4] = (short)f2bf(hi[kk].x); a[5] = (short)f2bf(hi[kk].y);
            a[6] = (short)f2bf(hi[kk].z); a[7] = (short)f2bf(hi[kk].w);
            afrag[kk] = a;
        }
        mfma_store_tile(afrag, wT, hiddenBf, t1 * 16, n16, quad);
    }
}

// ---------------------------------------------------------------------------
// Bin kernel: 489 blocks, 8 edges/thread, register-batched loads (round 3).
// Round 7: payload packs adj as (bf16_hi << 16) | bf16_lo so the agg's
// selector needs only shifts+cndmask; node-local is 4 bits now.
// LDS 75 KB -> 2 blocks/CU.
// ---------------------------------------------------------------------------
__global__ __launch_bounds__(256, 2) void bin_kernel(
    const int* __restrict__ row, const int* __restrict__ col,
    const float* __restrict__ adj, int* __restrict__ gCursor,
    int2* __restrict__ edges)
{
    __shared__ int cnt[N_BKT];
    __shared__ int cbase[N_BKT];
    __shared__ int cur[N_BKT];

    const int t  = threadIdx.x;
    const int e0 = blockIdx.x * EPB;

    for (int i = t; i < N_BKT; i += 256) cnt[i] = 0;
    __syncthreads();

    int rreg[8];
#pragma unroll
    for (int u = 0; u < 8; ++u) {
        int e = e0 + t + u * 256;
        rreg[u] = (e < N_EDGES) ? row[e] : -1;
    }
#pragma unroll
    for (int u = 0; u < 8; ++u)
        if (rreg[u] >= 0) atomicAdd(&cnt[rreg[u] >> BKT_SHIFT], 1);
    __syncthreads();

    for (int i = t; i < N_BKT; i += 256) {
        int c = cnt[i];
        cbase[i] = c ? atomicAdd(&gCursor[i], c) : 0;
        cur[i] = 0;
    }
    __syncthreads();

    int cc[8]; float vv[8];
#pragma unroll
    for (int u = 0; u < 8; ++u) {
        int e = e0 + t + u * 256;
        if (rreg[u] >= 0) { cc[u] = col[e]; vv[u] = adj[e]; }
        else              { cc[u] = 0;      vv[u] = 0.f;    }
    }
#pragma unroll
    for (int u = 0; u < 8; ++u) {
        int r = rreg[u];
        if (r >= 0) {
            int b = r >> BKT_SHIFT;
            int off = cbase[b] + atomicAdd(&cur[b], 1);
            if (off < BKT_CAP) {  // capacity guard (never trips)
                unsigned hi = f2bf(vv[u]);
                float hif  = __uint_as_float(hi << 16);
                unsigned lo = f2bf(vv[u] - hif);
                edges[b * BKT_CAP + off] =
                    make_int2(((r & (NODES_PER_BKT - 1)) << 17) | cc[u],
                              (int)((hi << 16) | lo));
            }
        }
    }
}

// ---------------------------------------------------------------------------
// Round 7: MFMA aggregation. One wave per 16-node bucket. Per 64-edge group:
// two K=32 sub-chunks. Stage H transposed: lane=dim writes hT[dim][edge]
// (u16x4 packed b64 writes); selector A-frag built from shfl'd records:
// a[j] = (node_local(e)==n16) ? adj_bf16 : 0 for e = s*32 + quad*8 + j —
// exactly the verified 16x16x32 A-layout (row=lane&15, k=quad*8+j). B-frag
// read = contiguous short8 at hT[ct*16+n16][quad*8] (wT pattern). adj hi/lo
// -> 2 MFMAs share each B. Zero-padded lanes (rec=0) contribute adj=0: the
// inner loops need no tail handling. No LDS RMW chain, no atomics, no
// barriers. LDS 8 x 5120 B = 40 KB.
// ---------------------------------------------------------------------------
__global__ __launch_bounds__(512) void agg_mfma_kernel(
    const unsigned short* __restrict__ hiddenBf,
    const int2* __restrict__ edges, const int* __restrict__ gCursor,
    const float* __restrict__ prelu_a, float* __restrict__ out)
{
    __shared__ unsigned short hT[8][64][40];   // per-wave [dim][edge], pitch 40

    const int t    = threadIdx.x;
    const int lane = t & 63;
    const int wid  = t >> 6;
    const int bucket = blockIdx.x * 8 + wid;
    if (bucket >= N_BKT) return;   // safe: no barriers in this kernel

    const int n16  = lane & 15;
    const int quad = lane >> 4;

    unsigned short (*H)[40] = hT[wid];

    f32x4 acc[4] = {{0.f,0.f,0.f,0.f},{0.f,0.f,0.f,0.f},
                    {0.f,0.f,0.f,0.f},{0.f,0.f,0.f,0.f}};

    const int base = bucket * BKT_CAP;
    int size = gCursor[bucket];
    if (size > BKT_CAP) size = BKT_CAP;

    for (int i0 = 0; i0 < size; i0 += 64) {
        int take = size - i0;
        if (take > 64) take = 64;
        int2 rec = make_int2(0, 0);
        if (lane < take) rec = edges[base + i0 + lane];

#pragma unroll
        for (int s = 0; s < 2; ++s) {
            // ---- stage 32 rows transposed: lane = dim, 16-deep gathers ----
#pragma unroll
            for (int g = 0; g < 2; ++g) {
                int cc[16]; unsigned short hh[16];
#pragma unroll
                for (int u = 0; u < 16; ++u)
                    cc[u] = __builtin_amdgcn_readlane(rec.x, s * 32 + g * 16 + u)
                            & 0x1FFFF;
#pragma unroll
                for (int u = 0; u < 16; ++u)
                    hh[u] = hiddenBf[(size_t)cc[u] * D_OUT + lane];
#pragma unroll
                for (int u = 0; u < 16; u += 4) {
                    u16x4 p;
                    p[0] = hh[u]; p[1] = hh[u + 1];
                    p[2] = hh[u + 2]; p[3] = hh[u + 3];
                    *(u16x4*)&H[lane][g * 16 + u] = p;
                }
            }

            // ---- selector A-fragments (hi/lo) ----
            short8 ahi, alo;
#pragma unroll
            for (int j = 0; j < 8; ++j) {
                int e  = s * 32 + quad * 8 + j;
                int rx = __shfl(rec.x, e);
                int ry = __shfl(rec.y, e);
                bool m = (((unsigned)rx >> 17) == (unsigned)n16);
                ahi[j] = m ? (short)((unsigned)ry >> 16) : (short)0;
                alo[j] = m ? (short)(ry & 0xFFFF)        : (short)0;
            }

            // ---- B-frags + MFMA (compiler orders ds ops: alias-unknown) ----
#pragma unroll
            for (int ct = 0; ct < 4; ++ct) {
                short8 b = *(const short8*)&H[ct * 16 + n16][quad * 8];
                acc[ct] = __builtin_amdgcn_mfma_f32_16x16x32_bf16(
                    ahi, b, acc[ct], 0, 0, 0);
                acc[ct] = __builtin_amdgcn_mfma_f32_16x16x32_bf16(
                    alo, b, acc[ct], 0, 0, 0);
            }
        }
    }

    // epilogue: PReLU + store. D layout: row(node)=quad*4+reg, col(dim)=n16.
    const float a = prelu_a[0];
    const int node0 = bucket * NODES_PER_BKT;
#pragma unroll
    for (int ct = 0; ct < 4; ++ct)
#pragma unroll
        for (int r = 0; r < 4; ++r) {
            float sv = acc[ct][r];
            out[(size_t)(node0 + quad * 4 + r) * D_OUT + ct * 16 + n16]
                = sv > 0.f ? sv : a * sv;
        }
}

// ---------------------------------------------------------------------------
extern "C" void kernel_launch(void* const* d_in, const int* in_sizes, int n_in,
                              void* d_out, int out_size, void* d_ws, size_t ws_size,
                              hipStream_t stream)
{
    const float* x       = (const float*)d_in[0];
    const float* w       = (const float*)d_in[1];
    const float* adj     = (const float*)d_in[2];
    const float* prelu_a = (const float*)d_in[3];
    const int*   row     = (const int*)d_in[4];
    const int*   col     = (const int*)d_in[5];
    float* out = (float*)d_out;

    // workspace layout (bytes)
    char* ws = (char*)d_ws;
    unsigned short* hiddenBf = (unsigned short*)(ws);        // 12,800,000
    int2*  edges    = (int2*)        (ws + 12800000);        // 12,800,000 (6250*256*8)
    int*   gCursor  = (int*)         (ws + 25600000);        //     25,000

    // no hipMemsetAsync: gemm block 0 zeroes gCursor (stream-ordered).
    gemm_kernel<<<GEMM_BLOCKS, 256, 0, stream>>>(x, w, hiddenBf, gCursor);

    bin_kernel<<<BIN_BLOCKS, 256, 0, stream>>>(row, col, adj, gCursor, edges);

    agg_mfma_kernel<<<AGG_BLOCKS, 512, 0, stream>>>(
        hiddenBf, edges, gCursor, prelu_a, out);
}